// Round 3
// baseline (37.825 us; speedup 1.0000x reference)
//
#include <hip/hip_runtime.h>
#include <math.h>

#define D 64
#define BATCH 16384
#define SEQ 50
#define HALF 25

// Two 64-lane waves per batch row; wave p owns seq positions [p*25, p*25+25).
//  Phase L: 25 coalesced 256B row loads (lane = dim), rows resident in e[25]
//  Phase S: fused butterfly reduce (step 0 computed straight from e -> red[13]),
//           5 more steps -> lane l holds dot(row_l, w) for l<25
//  LDS exchange of masked scores; both waves compute the 50-wide softmax
//  Phase P: partial pooled over own 25 rows; wave1 -> LDS, wave0 adds + stores
__global__ __launch_bounds__(256, 8) void attn_pool_kernel(
    const int* __restrict__ idx,
    const float* __restrict__ emb,
    const float* __restrict__ w,     // [D]
    const float* __restrict__ bias,  // [1]
    float* __restrict__ out)         // [BATCH][D]
{
    __shared__ float s_scores[2][64];
    __shared__ float s_pool[2][64];
    __shared__ int   s_any[2][2];

    const int wib  = (int)(threadIdx.x >> 6);  // 0..3
    const int lane = (int)(threadIdx.x & 63);
    const int rowb = wib >> 1;                 // row within block
    const int p    = wib & 1;                  // which half of the sequence
    const int row  = (int)blockIdx.x * 2 + rowb;

    // ---- idx for this half; lane j (<25) holds idx[row][p*25+j] ----
    int my_idx = 0;
    if (lane < HALF) my_idx = idx[row * SEQ + p * HALF + lane];
    bool valid = (lane < HALF) && (my_idx != 0);
    unsigned long long ballot = __ballot(valid);

    const float wl = w[lane];

    // ---- Phase L: coalesced row loads, register resident ----
    float e[HALF];
    #pragma unroll
    for (int l = 0; l < HALF; ++l) {
        int il = __builtin_amdgcn_readlane(my_idx, l);   // SGPR row base
        e[l] = emb[(size_t)il * D + lane];               // 256B coalesced
    }

    // ---- Phase S: butterfly reduce, step 0 fused from e (no red[25]) ----
    float red[13];
    {
        const bool up = (lane & 1) != 0;
        #pragma unroll
        for (int j = 0; j < 13; ++j) {
            float a = e[2 * j] * wl;
            float b = (2 * j + 1 < HALF) ? e[2 * j + 1] * wl : 0.0f;
            float send = up ? a : b;
            float recv = __shfl_xor(send, 1);
            red[j] = (up ? b : a) + recv;
        }
    }
    static const int LENS[6] = {13, 7, 4, 2, 1, 1};
    #pragma unroll
    for (int step = 1; step < 6; ++step) {
        const int m = 1 << step;
        const int len = LENS[step - 1];
        const int npair = LENS[step];
        const bool up = (lane & m) != 0;
        #pragma unroll
        for (int j = 0; j < npair; ++j) {
            float a = red[2 * j];
            float b = (2 * j + 1 < len) ? red[2 * j + 1] : 0.0f;
            float send = up ? a : b;
            float recv = __shfl_xor(send, m);
            red[j] = (up ? b : a) + recv;
        }
    }
    float score = red[0] + bias[0];   // lane l (<25) holds score[p*25+l]

    // ---- publish masked scores ----
    if (lane < HALF) s_scores[rowb][p * HALF + lane] = valid ? score : -INFINITY;
    if (lane == 0)   s_any[rowb][p] = (ballot != 0ULL) ? 1 : 0;
    __syncthreads();

    // ---- 50-wide masked softmax (computed redundantly by both waves) ----
    float v = (lane < SEQ) ? s_scores[rowb][lane] : -INFINITY;
    if (lane == 0 && s_any[rowb][0] == 0 && s_any[rowb][1] == 0)
        v = 0.0f;   // all-pad row: force l=0 (its emb row is zeros anyway)

    float m = v;
    #pragma unroll
    for (int s = 1; s < 64; s <<= 1) m = fmaxf(m, __shfl_xor(m, s));
    float pr = __expf(v - m);          // exp(-inf - m) = 0 for masked lanes
    float sum = pr;
    #pragma unroll
    for (int s = 1; s < 64; s <<= 1) sum += __shfl_xor(sum, s);
    float attn = pr / sum;             // attn for global position `lane`

    // ---- Phase P: partial pooled over own 25 rows ----
    float pooled = 0.0f;
    #pragma unroll
    for (int j = 0; j < HALF; ++j) {
        float a = __uint_as_float(
            __builtin_amdgcn_readlane(__float_as_uint(attn), p * HALF + j));
        pooled = fmaf(a, e[j], pooled);
    }

    if (p == 1) s_pool[rowb][lane] = pooled;
    __syncthreads();
    if (p == 0) out[row * D + lane] = pooled + s_pool[rowb][lane];
}

extern "C" void kernel_launch(void* const* d_in, const int* in_sizes, int n_in,
                              void* d_out, int out_size, void* d_ws, size_t ws_size,
                              hipStream_t stream) {
    const int*   idx  = (const int*)d_in[0];
    const float* emb  = (const float*)d_in[1];
    const float* w    = (const float*)d_in[2];
    const float* bias = (const float*)d_in[3];
    float* out = (float*)d_out;

    const int threads = 256;                 // 4 waves = 2 rows per block
    const int blocks = BATCH / 2;            // 8192
    attn_pool_kernel<<<blocks, threads, 0, stream>>>(idx, emb, w, bias, out);
}